// Round 12
// baseline (202.129 us; speedup 1.0000x reference)
//
#include <hip/hip_runtime.h>
#include <math.h>

typedef _Float16 f16;
typedef __attribute__((ext_vector_type(8))) f16 f16x8;
typedef __attribute__((ext_vector_type(4))) float f32x4;
typedef __attribute__((ext_vector_type(4))) int   i32x4;

__device__ __forceinline__ short f2h(float f) {      // RNE f32->f16, bits
    return __builtin_bit_cast(short, (f16)f);
}

__device__ __forceinline__ void gload16(const void* g, void* l) {
    __builtin_amdgcn_global_load_lds(
        (const __attribute__((address_space(1))) unsigned int*)g,
        (__attribute__((address_space(3))) unsigned int*)l, 16, 0, 0);
}

#define MFMA16(A, B, C) __builtin_amdgcn_mfma_f32_16x16x32_f16(A, B, C, 0, 0, 0)
#define EXP2(x) __builtin_amdgcn_exp2f(x)    // raw v_exp_f32

// ---------------------------------------------------------------------------
// fp32 -> single f16 conversion. Segments (float4 units): q 524288 |
// kv 1048576 | Wq,Wk,Wv,Wo 65536 each. Thread = one float4.
// ---------------------------------------------------------------------------
__global__ __launch_bounds__(256) void convert_kernel(
    const float* __restrict__ q, const float* __restrict__ kv,
    const float* __restrict__ Wq, const float* __restrict__ Wk,
    const float* __restrict__ Wv, const float* __restrict__ Wo,
    short* __restrict__ cq, short* __restrict__ ckv,
    short* __restrict__ wq, short* __restrict__ wk,
    short* __restrict__ wv, short* __restrict__ wo)
{
    int g = blockIdx.x * 256 + threadIdx.x;
    const float* src; short* dst; int local;
    if      (g <  524288) { src = q;  dst = cq;  local = g; }
    else if (g < 1572864) { src = kv; dst = ckv; local = g -  524288; }
    else if (g < 1638400) { src = Wq; dst = wq;  local = g - 1572864; }
    else if (g < 1703936) { src = Wk; dst = wk;  local = g - 1638400; }
    else if (g < 1769472) { src = Wv; dst = wv;  local = g - 1703936; }
    else                  { src = Wo; dst = wo;  local = g - 1769472; }
    float4 v = *(const float4*)(src + (size_t)local * 4);
    short4 hv; short* hp = (short*)&hv;
    hp[0] = f2h(v.x); hp[1] = f2h(v.y); hp[2] = f2h(v.z); hp[3] = f2h(v.w);
    *(short4*)(dst + (size_t)local * 4) = hv;
}

// ---------------------------------------------------------------------------
// Single-pass f16 GEMM core (R2-proven, BK=32): double-buffered LDS,
// stage(k+1) issued BEFORE compute(k), one vmcnt(0)+barrier per step.
// RT = rows per block (128 or 64), 128 cols, 4 waves (2x2).
// EP: 0 fp32 | 1 f16 scaled | 2 V-frag.
// ---------------------------------------------------------------------------
template<int RT, int EP>
__device__ __forceinline__ void gemm_core(
    short* As, short* Bs,          // As: [2][RT*32], Bs: [2][128*32]
    const short* __restrict__ X, const short* __restrict__ W,
    const float* __restrict__ bias, float scale,
    float* __restrict__ outF, short* __restrict__ outH,
    int m0, int n0)
{
    const int tid  = threadIdx.x;
    const int wave = tid >> 6, lane = tid & 63;
    const int quad = lane >> 4, col = lane & 15;
    const int wy = wave >> 1, wx = wave & 1;
    constexpr int MT  = RT / 32;         // per-wave 16-row m-tiles
    constexpr int ASZ = RT * 32;         // shorts per A buffer

    f32x4 acc[MT][4];
    #pragma unroll
    for (int i = 0; i < MT; ++i)
        #pragma unroll
        for (int j = 0; j < 4; ++j) acc[i][j] = (f32x4){0.f, 0.f, 0.f, 0.f};

    int aoff[MT], boff[4];
    #pragma unroll
    for (int t = 0; t < MT; ++t)
        aoff[t] = (wy * (RT / 2) + t * 16 + col) * 32 + quad * 8;
    #pragma unroll
    for (int t = 0; t < 4; ++t)
        boff[t] = (wx * 64 + t * 16 + col) * 32 + quad * 8;

    const short* Abase = X + (size_t)m0 * 512;
    const short* Bbase = W + (size_t)n0 * 512;

#define STAGE_G(BUF, KB) {                                                   \
    _Pragma("unroll")                                                        \
    for (int i = 0; i < RT / 64; ++i) {                                      \
        int p = i * 256 + tid; int r = p >> 2, qq = p & 3;                   \
        gload16(Abase + (size_t)r * 512 + (KB) + qq * 8,                     \
                &As[(BUF) * ASZ + (i * 256 + wave * 64) * 8]);               \
    }                                                                        \
    _Pragma("unroll")                                                        \
    for (int i = 0; i < 2; ++i) {                                            \
        int p = i * 256 + tid; int r = p >> 2, qq = p & 3;                   \
        gload16(Bbase + (size_t)r * 512 + (KB) + qq * 8,                     \
                &Bs[(BUF) * 4096 + (i * 256 + wave * 64) * 8]);              \
    }                                                                        \
}

    STAGE_G(0, 0);
    asm volatile("s_waitcnt vmcnt(0)" ::: "memory");
    __syncthreads();

    for (int kb = 0; kb < 512; kb += 32) {
        const int cur = (kb >> 5) & 1;
        if (kb + 32 < 512) STAGE_G(cur ^ 1, kb + 32);   // issue-ahead
        f16x8 a[MT], b[4];
        #pragma unroll
        for (int t = 0; t < MT; ++t) a[t] = *(const f16x8*)&As[cur * ASZ + aoff[t]];
        #pragma unroll
        for (int t = 0; t < 4; ++t)  b[t] = *(const f16x8*)&Bs[cur * 4096 + boff[t]];
        #pragma unroll
        for (int tm = 0; tm < MT; ++tm)
            #pragma unroll
            for (int tn = 0; tn < 4; ++tn)
                acc[tm][tn] = MFMA16(a[tm], b[tn], acc[tm][tn]);
        asm volatile("s_waitcnt vmcnt(0)" ::: "memory");  // next stage landed
        __syncthreads();                                   // all reads of cur done
    }
#undef STAGE_G

    #pragma unroll
    for (int tn = 0; tn < 4; ++tn) {
        int ng = n0 + wx * 64 + tn * 16 + col;
        float bb = bias[ng];
        #pragma unroll
        for (int tm = 0; tm < MT; ++tm) {
            int mb = m0 + wy * (RT / 2) + tm * 16 + quad * 4;
            if constexpr (EP == 2) {
                // V-fragment order for attention PV B-operand.
                int bb_ = mb >> 12, kvg = mb & 4095;
                int tile = kvg >> 7, kv128 = kvg & 127;
                int t01 = (kv128 >> 6) & 1, sv = (kv128 >> 4) & 3, qd = (kv128 >> 2) & 3;
                int hh = ng >> 6, dd = ng & 63, dt = dd >> 4, d15 = dd & 15;
                size_t base = ((((size_t)((bb_ * 8 + hh) * 32 + tile) * 16)
                               + sv * 4 + dt) * 64 + qd * 16 + d15) * 8 + t01 * 4;
                short4 s4; short* sp = (short*)&s4;
                #pragma unroll
                for (int r = 0; r < 4; ++r) sp[r] = f2h(acc[tm][tn][r] + bb);
                *(short4*)&outH[base] = s4;
            } else if constexpr (EP == 1) {
                #pragma unroll
                for (int r = 0; r < 4; ++r)
                    outH[(size_t)(mb + r) * 512 + ng] =
                        f2h((acc[tm][tn][r] + bb) * scale);
            } else {
                #pragma unroll
                for (int r = 0; r < 4; ++r)
                    outF[(size_t)(mb + r) * 512 + ng] = acc[tm][tn][r] + bb;
            }
        }
    }
}

// Fused Q/K/V projections: blocks [0,128) Q | [128,384) K | [384,640) V.
__global__ __launch_bounds__(256) void fused_qkv_gemm_kernel(
    const short* __restrict__ cq, const short* __restrict__ ckv,
    const short* __restrict__ wq, const short* __restrict__ wk,
    const short* __restrict__ wv,
    const float* __restrict__ bq, const float* __restrict__ bk,
    const float* __restrict__ bv, float qscale,
    short* __restrict__ Qh, short* __restrict__ Kh, short* __restrict__ Vf)
{
    __shared__ short As[2 * 128 * 32], Bs[2 * 128 * 32];
    int bi = blockIdx.x;
    if (bi < 128) {
        gemm_core<128, 1>(As, Bs, cq, wq, bq, qscale, nullptr, Qh,
                          (bi >> 2) * 128, (bi & 3) * 128);
    } else if (bi < 384) {
        bi -= 128;
        gemm_core<128, 1>(As, Bs, ckv, wk, bk, 1.0f, nullptr, Kh,
                          (bi >> 2) * 128, (bi & 3) * 128);
    } else {
        bi -= 384;
        gemm_core<128, 2>(As, Bs, ckv, wv, bv, 1.0f, nullptr, Vf,
                          (bi >> 2) * 128, (bi & 3) * 128);
    }
}

// O-projection: 64-row tiles -> 256 blocks.
__global__ __launch_bounds__(256) void gemm_o_kernel(
    const short* __restrict__ X, const short* __restrict__ W,
    const float* __restrict__ bias, float* __restrict__ outF)
{
    __shared__ short As[2 * 64 * 32], Bs[2 * 128 * 32];
    gemm_core<64, 0>(As, Bs, X, W, bias, 1.0f, outF, nullptr,
                     (int)(blockIdx.x >> 2) * 64, (int)(blockIdx.x & 3) * 128);
}

// ---------------------------------------------------------------------------
// RoPE on f16 K in place; per-block LDS sin/cos table (4 rows x 32 freqs).
// ---------------------------------------------------------------------------
__global__ __launch_bounds__(256) void rope_kernel(short* __restrict__ Kh)
{
    __shared__ float2 tbl[4][32];
    const int t = threadIdx.x;
    const int g = blockIdx.x * 256 + t;     // 524288 total (8192 rows x 64)
    if (t < 128) {
        int p = t >> 5, i = t & 31;
        int pos = (blockIdx.x * 4 + p) & 4095;
        float fr = expf((float)i * -0.28782313662425576f);
        float sv, cv;
        sincosf((float)pos * fr, &sv, &cv);
        tbl[p][i] = make_float2(cv, sv);
    }
    __syncthreads();

    int row = g >> 6;
    int c8  = (g & 63) * 8;
    size_t off = (size_t)row * 512 + c8;
    f16x8 hv = *(const f16x8*)&Kh[off];
    float x[8];
    #pragma unroll
    for (int j = 0; j < 8; ++j) x[j] = (float)hv[j];
    const int rl = row & 3;
    const int ib = (c8 & 63) >> 1;
    #pragma unroll
    for (int p = 0; p < 4; ++p) {
        float2 cs = tbl[rl][ib + p];
        float e = x[2 * p], o = x[2 * p + 1];
        x[2 * p]     = e * cs.x - o * cs.y;
        x[2 * p + 1] = o * cs.x + e * cs.y;
    }
    #pragma unroll
    for (int j = 0; j < 8; ++j) hv[j] = (f16)x[j];
    *(f16x8*)&Kh[off] = hv;
}

// ---------------------------------------------------------------------------
// MFMA flash attention, QT=2 + LDS-staged K (unified-register diet).
// R11 finding: true per-wave footprint is ~230 UNIFIED regs (VGPR_Count
// shows only the arch portion) -> hard 2 waves/SIMD regardless of grid.
// Diet: QT=2 (acc 32 not 64) and K staged in LDS via wave-private
// global_load_lds parity double-buffer (R0-proven; no VGPR residency for
// K buffers, no __syncthreads in loop, counted vmcnt gates). V keeps R2's
// 2-body register double-buffer. Estimated ~145 unified -> 3 waves/SIMD.
// Grid 1024 = qt(64) x bh(16). LDS 32 KB staging; 17 KB epilogue overlaid.
// vmcnt math: steady state allows exactly {STG(I+1)=4, LDV(I+1)=4} ->
// vmcnt(8); prologue 16 issued -> vmcnt(12) forces K(0) complete.
// (256,2): cap 256, NEVER force min-waves (R3/R7/R8/R9 spills).
// ---------------------------------------------------------------------------
__global__ __launch_bounds__(256, 2) void attn_mfma_kernel(
    const short* __restrict__ Qh, const short* __restrict__ Kh,
    const short* __restrict__ Vfrag, short* __restrict__ AO)
{
    __shared__ char smem[32768];   // loop: 4 waves x 8 KB K parity staging
                                   // epilogue: Opart[4][32*33] + Lpart[4][32]

    const int tid  = threadIdx.x;
    const int wave = tid >> 6;
    const int lane = tid & 63;
    const int quad = lane >> 4;
    const int l15  = lane & 15;

    const int bh = blockIdx.x & 15;      // XCD-local: blk%8 == h under RR
    const int qt = blockIdx.x >> 4;      // 64 q-tiles of 32 rows
    const int b  = bh >> 3, h = bh & 7;
    const int qb = qt * 32;

    // ---- Q as B-fragments (32 q rows), f16, scale pre-folded ----
    f16x8 qf[2][2];
    #pragma unroll
    for (int tq = 0; tq < 2; ++tq)
        #pragma unroll
        for (int c = 0; c < 2; ++c)
            qf[tq][c] = *(const f16x8*)&Qh[((size_t)(b * 2048 + qb + tq * 16 + l15)) * 512
                                           + h * 64 + c * 32 + quad * 8];

    f32x4 o[2][4];    // [tq][dt] O partials over this wave's kv
    f32x4 l4[2];      // [tq] row sums (ones-column PV)
    #pragma unroll
    for (int i = 0; i < 2; ++i) {
        l4[i] = (f32x4){0.f, 0.f, 0.f, 0.f};
        #pragma unroll
        for (int j = 0; j < 4; ++j) o[i][j] = (f32x4){0.f, 0.f, 0.f, 0.f};
    }

    const f32x4 zero4 = (f32x4){0.f, 0.f, 0.f, 0.f};
    f16x8 vones;
    #pragma unroll
    for (int j = 0; j < 8; ++j) vones[j] = (f16)1.0f;

    // per-lane K global base (this wave's kv rows); V per-lane base
    const short* kp = Kh + ((size_t)(b * 4096 + wave * 16 + l15)) * 512
                      + h * 64 + quad * 8;
    const short* vbase = Vfrag + (size_t)(b * 8 + h) * 262144
                         + ((size_t)(wave * 4) * 64 + lane) * 8;

    // wave-private K staging: parity p at +p*2048 shorts, frag f=s*2+c at
    // +f*512, lane's data lands at +lane*8 (HW: base + lane*16B).
    short* sw = (short*)smem + wave * 4096;   // 8 KB per wave

#define STG(I, P) { const short* _k = kp + (size_t)(I) * 65536;              \
    short* _d = sw + (P) * 2048;                                             \
    gload16(_k,              _d);                                            \
    gload16(_k + 32,         _d + 512);                                      \
    gload16(_k + 32768,      _d + 1024);                                     \
    gload16(_k + 32768 + 32, _d + 1536); }

#define LDV(DST, I) { const short* _v = vbase + (size_t)(I) * 8192;          \
    DST[0] = *(const f16x8*)(_v);                                            \
    DST[1] = *(const f16x8*)(_v + 512);                                      \
    DST[2] = *(const f16x8*)(_v + 1024);                                     \
    DST[3] = *(const f16x8*)(_v + 1536); }

#define QKL(P) {                                                             \
    const short* _kb = sw + (P) * 2048;                                      \
    f16x8 k0 = *(const f16x8*)(_kb + lane * 8);                              \
    f16x8 k1 = *(const f16x8*)(_kb + 512 + lane * 8);                        \
    f16x8 k2 = *(const f16x8*)(_kb + 1024 + lane * 8);                       \
    f16x8 k3 = *(const f16x8*)(_kb + 1536 + lane * 8);                       \
    __builtin_amdgcn_s_setprio(1);                                           \
    _Pragma("unroll")                                                        \
    for (int t = 0; t < 2; ++t) {                                            \
        s0[t] = MFMA16(k0, qf[t][0], zero4);                                 \
        s0[t] = MFMA16(k1, qf[t][1], s0[t]);                                 \
        s1[t] = MFMA16(k2, qf[t][0], zero4);                                 \
        s1[t] = MFMA16(k3, qf[t][1], s1[t]);                                 \
    }                                                                        \
    __builtin_amdgcn_s_setprio(0); }

#define FIN(VP) {                                                            \
    _Pragma("unroll")                                                        \
    for (int t = 0; t < 2; ++t) {                                            \
        float e0 = EXP2(s0[t][0]), e1 = EXP2(s0[t][1]);                      \
        float e2 = EXP2(s0[t][2]), e3 = EXP2(s0[t][3]);                      \
        float e4 = EXP2(s1[t][0]), e5 = EXP2(s1[t][1]);                      \
        float e6 = EXP2(s1[t][2]), e7 = EXP2(s1[t][3]);                      \
        i32x4 pw;                                                            \
        pw.x = __builtin_bit_cast(int, __builtin_amdgcn_cvt_pkrtz(e0, e1));  \
        pw.y = __builtin_bit_cast(int, __builtin_amdgcn_cvt_pkrtz(e2, e3));  \
        pw.z = __builtin_bit_cast(int, __builtin_amdgcn_cvt_pkrtz(e4, e5));  \
        pw.w = __builtin_bit_cast(int, __builtin_amdgcn_cvt_pkrtz(e6, e7));  \
        f16x8 p8 = __builtin_bit_cast(f16x8, pw);                            \
        __builtin_amdgcn_s_setprio(1);                                       \
        _Pragma("unroll")                                                    \
        for (int dt = 0; dt < 4; ++dt)                                       \
            o[t][dt] = MFMA16(p8, VP[dt], o[t][dt]);                         \
        l4[t] = MFMA16(p8, vones, l4[t]);                                    \
        __builtin_amdgcn_s_setprio(0);                                       \
    } }

    // BODY(I): stage K(I+1); finish iter I-1 (V(I-1) in VP); load V(I+1)
    // into VP (2-body cover); gate on vmcnt(8) = {STG(I+1), LDV(I+1)}
    // outstanding, K(I)+V(I) forced complete; QK from LDS parity I&1.
    // I=31 stages K(32)/loads V(32) from adjacent allocated workspace.
#define BODY(I, VP) {                                                        \
    STG((I) + 1, ((I) + 1) & 1);                                             \
    FIN(VP);                                                                 \
    LDV(VP, (I) + 1);                                                        \
    asm volatile("s_waitcnt vmcnt(8)" ::: "memory");                         \
    QKL((I) & 1); }

    f16x8 vA[4], vB[4];
    f32x4 s0[2], s1[2];

    // prologue: K0(p0), V0, K1(p1), V1 in flight; gate K0; QK(0)
    STG(0, 0); LDV(vA, 0); STG(1, 1); LDV(vB, 1);
    asm volatile("s_waitcnt vmcnt(12)" ::: "memory");
    QKL(0);

    #pragma unroll 1
    for (int j = 1; j < 31; j += 2) {
        BODY(j,     vA);     // FIN(V(j-1)), load V(j+1) -> vA
        BODY(j + 1, vB);
    }
    BODY(31, vA);
    FIN(vB);          // iter 31: s = QK(31), V(31) in vB

#undef BODY
#undef FIN
#undef QKL
#undef LDV
#undef STG

    // drain tail staging DMAs before repurposing LDS across waves
    asm volatile("s_waitcnt vmcnt(0)" ::: "memory");
    __syncthreads();

    float* Opart = (float*)smem;               // [4][32*33]
    float* Lpart = (float*)(smem + 16896);     // [4][32]

    // ---- two-pass cross-wave O reduction (pass 0: d 0..31, 1: 32..63) ----
    float inv_save[4];
    #pragma unroll
    for (int pass = 0; pass < 2; ++pass) {
        if (pass) __syncthreads();
        #pragma unroll
        for (int tq = 0; tq < 2; ++tq)
            #pragma unroll
            for (int dh = 0; dh < 2; ++dh) {
                int dt = pass * 2 + dh;
                #pragma unroll
                for (int r = 0; r < 4; ++r)
                    Opart[wave * (32 * 33) + (tq * 16 + quad * 4 + r) * 33 + dh * 16 + l15] = o[tq][dt][r];
            }
        if (pass == 0 && l15 == 0) {
            #pragma unroll
            for (int tq = 0; tq < 2; ++tq)
                #pragma unroll
                for (int r = 0; r < 4; ++r)
                    Lpart[wave * 32 + tq * 16 + quad * 4 + r] = l4[tq][r];
        }
        __syncthreads();
        #pragma unroll
        for (int r = 0; r < 4; ++r) {
            int qq = wave * 8 + r * 2 + (lane >> 5);   // local q row 0..31
            int d  = lane & 31;
            float v = Opart[0 * (32 * 33) + qq * 33 + d] + Opart[1 * (32 * 33) + qq * 33 + d]
                    + Opart[2 * (32 * 33) + qq * 33 + d] + Opart[3 * (32 * 33) + qq * 33 + d];
            float inv;
            if (pass == 0) {
                float l = Lpart[qq] + Lpart[32 + qq] + Lpart[64 + qq] + Lpart[96 + qq];
                inv = 1.0f / l;
                inv_save[r] = inv;
            } else {
                inv = inv_save[r];
            }
            float val = v * inv;
            size_t oo = ((size_t)(b * 2048 + qb + qq)) * 512 + h * 64 + pass * 32 + d;
            AO[oo] = f2h(val);
        }
    }
}

// ---------------------------------------------------------------------------
extern "C" void kernel_launch(void* const* d_in, const int* in_sizes, int n_in,
                              void* d_out, int out_size, void* d_ws, size_t ws_size,
                              hipStream_t stream) {
    const float* q  = (const float*)d_in[0];
    const float* kv = (const float*)d_in[1];
    const float* Wq = (const float*)d_in[2];
    const float* bq = (const float*)d_in[3];
    const float* Wk = (const float*)d_in[4];
    const float* bk = (const float*)d_in[5];
    const float* Wv = (const float*)d_in[6];
    const float* bv = (const float*)d_in[7];
    const float* Wo = (const float*)d_in[8];
    const float* bo = (const float*)d_in[9];
    float* out = (float*)d_out;

    char* ws = (char*)d_ws;
    const size_t MB = 1024 * 1024;
    short* cq  = (short*)(ws + 0 * MB);    // 4 MB
    short* ckv = (short*)(ws + 4 * MB);    // 8 MB
    short* wq  = (short*)(ws + 12 * MB);   // 512 KB each
    short* wk  = wq + 262144;
    short* wv  = wk + 262144;
    short* wo  = wv + 262144;
    short* Qh  = (short*)(ws + 14 * MB);   // 4 MB
    short* Kh  = (short*)(ws + 18 * MB);   // 8 MB (tail K staging reads spill into Vf: allocated)
    short* Vf  = (short*)(ws + 26 * MB);   // 8 MB (tail V prefetch reads spill into AO: allocated)
    short* AO  = (short*)(ws + 34 * MB);   // 4 MB

    // 0.125 (1/sqrt(Dh)) * log2(e), so attention exp is a bare exp2.
    const float qscale = 0.18033688011112043f;

    dim3 blk(256);
    convert_kernel<<<7168, blk, 0, stream>>>(
        q, kv, Wq, Wk, Wv, Wo, cq, ckv, wq, wk, wv, wo);

    fused_qkv_gemm_kernel<<<640, blk, 0, stream>>>(
        cq, ckv, wq, wk, wv, bq, bk, bv, qscale, Qh, Kh, Vf);

    rope_kernel<<<2048, blk, 0, stream>>>(Kh);

    attn_mfma_kernel<<<1024, blk, 0, stream>>>(Qh, Kh, Vf, AO);

    gemm_o_kernel<<<256, blk, 0, stream>>>(AO, wo, bo, out);
}

// Round 13
// 169.223 us; speedup vs baseline: 1.1945x; 1.1945x over previous
//
#include <hip/hip_runtime.h>
#include <math.h>

typedef _Float16 f16;
typedef __attribute__((ext_vector_type(8))) f16 f16x8;
typedef __attribute__((ext_vector_type(4))) float f32x4;
typedef __attribute__((ext_vector_type(4))) int   i32x4;

__device__ __forceinline__ short f2h(float f) {      // RNE f32->f16, bits
    return __builtin_bit_cast(short, (f16)f);
}

__device__ __forceinline__ void gload16(const void* g, void* l) {
    __builtin_amdgcn_global_load_lds(
        (const __attribute__((address_space(1))) unsigned int*)g,
        (__attribute__((address_space(3))) unsigned int*)l, 16, 0, 0);
}

#define MFMA16(A, B, C) __builtin_amdgcn_mfma_f32_16x16x32_f16(A, B, C, 0, 0, 0)
#define EXP2(x) __builtin_amdgcn_exp2f(x)    // raw v_exp_f32

// ---------------------------------------------------------------------------
// fp32 -> single f16 conversion. Segments (float4 units): q 524288 |
// kv 1048576 | Wq,Wk,Wv,Wo 65536 each. Thread = one float4.
// ---------------------------------------------------------------------------
__global__ __launch_bounds__(256) void convert_kernel(
    const float* __restrict__ q, const float* __restrict__ kv,
    const float* __restrict__ Wq, const float* __restrict__ Wk,
    const float* __restrict__ Wv, const float* __restrict__ Wo,
    short* __restrict__ cq, short* __restrict__ ckv,
    short* __restrict__ wq, short* __restrict__ wk,
    short* __restrict__ wv, short* __restrict__ wo)
{
    int g = blockIdx.x * 256 + threadIdx.x;
    const float* src; short* dst; int local;
    if      (g <  524288) { src = q;  dst = cq;  local = g; }
    else if (g < 1572864) { src = kv; dst = ckv; local = g -  524288; }
    else if (g < 1638400) { src = Wq; dst = wq;  local = g - 1572864; }
    else if (g < 1703936) { src = Wk; dst = wk;  local = g - 1638400; }
    else if (g < 1769472) { src = Wv; dst = wv;  local = g - 1703936; }
    else                  { src = Wo; dst = wo;  local = g - 1769472; }
    float4 v = *(const float4*)(src + (size_t)local * 4);
    short4 hv; short* hp = (short*)&hv;
    hp[0] = f2h(v.x); hp[1] = f2h(v.y); hp[2] = f2h(v.z); hp[3] = f2h(v.w);
    *(short4*)(dst + (size_t)local * 4) = hv;
}

// ---------------------------------------------------------------------------
// Single-pass f16 GEMM core (R2-proven, BK=32): double-buffered LDS,
// stage(k+1) issued BEFORE compute(k), one vmcnt(0)+barrier per step.
// RT = rows per block (128 or 64), 128 cols, 4 waves (2x2).
// EP: 0 fp32 | 1 f16 scaled | 2 V-frag.
// ---------------------------------------------------------------------------
template<int RT, int EP>
__device__ __forceinline__ void gemm_core(
    short* As, short* Bs,          // As: [2][RT*32], Bs: [2][128*32]
    const short* __restrict__ X, const short* __restrict__ W,
    const float* __restrict__ bias, float scale,
    float* __restrict__ outF, short* __restrict__ outH,
    int m0, int n0)
{
    const int tid  = threadIdx.x;
    const int wave = tid >> 6, lane = tid & 63;
    const int quad = lane >> 4, col = lane & 15;
    const int wy = wave >> 1, wx = wave & 1;
    constexpr int MT  = RT / 32;         // per-wave 16-row m-tiles
    constexpr int ASZ = RT * 32;         // shorts per A buffer

    f32x4 acc[MT][4];
    #pragma unroll
    for (int i = 0; i < MT; ++i)
        #pragma unroll
        for (int j = 0; j < 4; ++j) acc[i][j] = (f32x4){0.f, 0.f, 0.f, 0.f};

    int aoff[MT], boff[4];
    #pragma unroll
    for (int t = 0; t < MT; ++t)
        aoff[t] = (wy * (RT / 2) + t * 16 + col) * 32 + quad * 8;
    #pragma unroll
    for (int t = 0; t < 4; ++t)
        boff[t] = (wx * 64 + t * 16 + col) * 32 + quad * 8;

    const short* Abase = X + (size_t)m0 * 512;
    const short* Bbase = W + (size_t)n0 * 512;

#define STAGE_G(BUF, KB) {                                                   \
    _Pragma("unroll")                                                        \
    for (int i = 0; i < RT / 64; ++i) {                                      \
        int p = i * 256 + tid; int r = p >> 2, qq = p & 3;                   \
        gload16(Abase + (size_t)r * 512 + (KB) + qq * 8,                     \
                &As[(BUF) * ASZ + (i * 256 + wave * 64) * 8]);               \
    }                                                                        \
    _Pragma("unroll")                                                        \
    for (int i = 0; i < 2; ++i) {                                            \
        int p = i * 256 + tid; int r = p >> 2, qq = p & 3;                   \
        gload16(Bbase + (size_t)r * 512 + (KB) + qq * 8,                     \
                &Bs[(BUF) * 4096 + (i * 256 + wave * 64) * 8]);              \
    }                                                                        \
}

    STAGE_G(0, 0);
    asm volatile("s_waitcnt vmcnt(0)" ::: "memory");
    __syncthreads();

    for (int kb = 0; kb < 512; kb += 32) {
        const int cur = (kb >> 5) & 1;
        if (kb + 32 < 512) STAGE_G(cur ^ 1, kb + 32);   // issue-ahead
        f16x8 a[MT], b[4];
        #pragma unroll
        for (int t = 0; t < MT; ++t) a[t] = *(const f16x8*)&As[cur * ASZ + aoff[t]];
        #pragma unroll
        for (int t = 0; t < 4; ++t)  b[t] = *(const f16x8*)&Bs[cur * 4096 + boff[t]];
        #pragma unroll
        for (int tm = 0; tm < MT; ++tm)
            #pragma unroll
            for (int tn = 0; tn < 4; ++tn)
                acc[tm][tn] = MFMA16(a[tm], b[tn], acc[tm][tn]);
        asm volatile("s_waitcnt vmcnt(0)" ::: "memory");  // next stage landed
        __syncthreads();                                   // all reads of cur done
    }
#undef STAGE_G

    #pragma unroll
    for (int tn = 0; tn < 4; ++tn) {
        int ng = n0 + wx * 64 + tn * 16 + col;
        float bb = bias[ng];
        #pragma unroll
        for (int tm = 0; tm < MT; ++tm) {
            int mb = m0 + wy * (RT / 2) + tm * 16 + quad * 4;
            if constexpr (EP == 2) {
                // V-fragment order for attention PV B-operand.
                int bb_ = mb >> 12, kvg = mb & 4095;
                int tile = kvg >> 7, kv128 = kvg & 127;
                int t01 = (kv128 >> 6) & 1, sv = (kv128 >> 4) & 3, qd = (kv128 >> 2) & 3;
                int hh = ng >> 6, dd = ng & 63, dt = dd >> 4, d15 = dd & 15;
                size_t base = ((((size_t)((bb_ * 8 + hh) * 32 + tile) * 16)
                               + sv * 4 + dt) * 64 + qd * 16 + d15) * 8 + t01 * 4;
                short4 s4; short* sp = (short*)&s4;
                #pragma unroll
                for (int r = 0; r < 4; ++r) sp[r] = f2h(acc[tm][tn][r] + bb);
                *(short4*)&outH[base] = s4;
            } else if constexpr (EP == 1) {
                #pragma unroll
                for (int r = 0; r < 4; ++r)
                    outH[(size_t)(mb + r) * 512 + ng] =
                        f2h((acc[tm][tn][r] + bb) * scale);
            } else {
                #pragma unroll
                for (int r = 0; r < 4; ++r)
                    outF[(size_t)(mb + r) * 512 + ng] = acc[tm][tn][r] + bb;
            }
        }
    }
}

// Fused Q/K/V projections, RT=64 tiles for occupancy (1280 blocks = 5/CU vs
// R2's 640 = 2.5/CU; latency-bound GEMM needs resident-block overlap):
// blocks [0,256) Q | [256,768) K | [768,1280) V. Same proven core template.
__global__ __launch_bounds__(256) void fused_qkv_gemm_kernel(
    const short* __restrict__ cq, const short* __restrict__ ckv,
    const short* __restrict__ wq, const short* __restrict__ wk,
    const short* __restrict__ wv,
    const float* __restrict__ bq, const float* __restrict__ bk,
    const float* __restrict__ bv, float qscale,
    short* __restrict__ Qh, short* __restrict__ Kh, short* __restrict__ Vf)
{
    __shared__ short As[2 * 64 * 32], Bs[2 * 128 * 32];
    int bi = blockIdx.x;
    if (bi < 256) {
        gemm_core<64, 1>(As, Bs, cq, wq, bq, qscale, nullptr, Qh,
                         (bi >> 2) * 64, (bi & 3) * 128);
    } else if (bi < 768) {
        bi -= 256;
        gemm_core<64, 1>(As, Bs, ckv, wk, bk, 1.0f, nullptr, Kh,
                         (bi >> 2) * 64, (bi & 3) * 128);
    } else {
        bi -= 768;
        gemm_core<64, 2>(As, Bs, ckv, wv, bv, 1.0f, nullptr, Vf,
                         (bi >> 2) * 64, (bi & 3) * 128);
    }
}

// O-projection: 64-row tiles -> 256 blocks.
__global__ __launch_bounds__(256) void gemm_o_kernel(
    const short* __restrict__ X, const short* __restrict__ W,
    const float* __restrict__ bias, float* __restrict__ outF)
{
    __shared__ short As[2 * 64 * 32], Bs[2 * 128 * 32];
    gemm_core<64, 0>(As, Bs, X, W, bias, 1.0f, outF, nullptr,
                     (int)(blockIdx.x >> 2) * 64, (int)(blockIdx.x & 3) * 128);
}

// ---------------------------------------------------------------------------
// RoPE on f16 K in place; per-block LDS sin/cos table (4 rows x 32 freqs).
// ---------------------------------------------------------------------------
__global__ __launch_bounds__(256) void rope_kernel(short* __restrict__ Kh)
{
    __shared__ float2 tbl[4][32];
    const int t = threadIdx.x;
    const int g = blockIdx.x * 256 + t;     // 524288 total (8192 rows x 64)
    if (t < 128) {
        int p = t >> 5, i = t & 31;
        int pos = (blockIdx.x * 4 + p) & 4095;
        float fr = expf((float)i * -0.28782313662425576f);
        float sv, cv;
        sincosf((float)pos * fr, &sv, &cv);
        tbl[p][i] = make_float2(cv, sv);
    }
    __syncthreads();

    int row = g >> 6;
    int c8  = (g & 63) * 8;
    size_t off = (size_t)row * 512 + c8;
    f16x8 hv = *(const f16x8*)&Kh[off];
    float x[8];
    #pragma unroll
    for (int j = 0; j < 8; ++j) x[j] = (float)hv[j];
    const int rl = row & 3;
    const int ib = (c8 & 63) >> 1;
    #pragma unroll
    for (int p = 0; p < 4; ++p) {
        float2 cs = tbl[rl][ib + p];
        float e = x[2 * p], o = x[2 * p + 1];
        x[2 * p]     = e * cs.x - o * cs.y;
        x[2 * p + 1] = o * cs.x + e * cs.y;
    }
    #pragma unroll
    for (int j = 0; j < 8; ++j) hv[j] = (f16)x[j];
    *(f16x8*)&Kh[off] = hv;
}

// ---------------------------------------------------------------------------
// MFMA flash attention: R2 EXACT (proven 49.8 us). QT=4 (64 q rows/block),
// grid 512, (256,2), ~120 arch-VGPR + MFMA accumulators in the unified
// file (~230 total) -> hard 2 waves/SIMD. Session-proven: QT=2 variants
// all ~85 us regardless of occupancy (R4/R12); forced occupancy spills
// (R3/R7/R8/R9); KV-split doesn't raise residency (R11). This structure
// is the local optimum -- DO NOT restructure.
//   body: LDK(next) -> FIN(prev) -> LDV(next) -> QK(cur)
// ---------------------------------------------------------------------------
__global__ __launch_bounds__(256, 2) void attn_mfma_kernel(
    const short* __restrict__ Qh, const short* __restrict__ Kh,
    const short* __restrict__ Vfrag, short* __restrict__ AO)
{
    __shared__ char smem[34816];   // epilogue: Opart 4*64*33 f32 + Lpart

    const int tid  = threadIdx.x;
    const int wave = tid >> 6;
    const int lane = tid & 63;
    const int quad = lane >> 4;
    const int l15  = lane & 15;

    const int bh = blockIdx.x & 15;      // XCD-local: blk%8 == h under RR
    const int qt = blockIdx.x >> 4;      // 32 q-tiles of 64 rows
    const int b  = bh >> 3, h = bh & 7;
    const int qb = qt * 64;

    // ---- Q as B-fragments (all 64 q rows), f16, scale pre-folded ----
    f16x8 qf[4][2];
    #pragma unroll
    for (int tq = 0; tq < 4; ++tq)
        #pragma unroll
        for (int c = 0; c < 2; ++c)
            qf[tq][c] = *(const f16x8*)&Qh[((size_t)(b * 2048 + qb + tq * 16 + l15)) * 512
                                           + h * 64 + c * 32 + quad * 8];

    f32x4 o[4][4];    // [tq][dt] O partials over this wave's kv
    f32x4 l4[4];      // [tq] row sums (ones-column PV)
    #pragma unroll
    for (int i = 0; i < 4; ++i) {
        l4[i] = (f32x4){0.f, 0.f, 0.f, 0.f};
        #pragma unroll
        for (int j = 0; j < 4; ++j) o[i][j] = (f32x4){0.f, 0.f, 0.f, 0.f};
    }

    const f32x4 zero4 = (f32x4){0.f, 0.f, 0.f, 0.f};
    f16x8 vones;
    #pragma unroll
    for (int j = 0; j < 8; ++j) vones[j] = (f16)1.0f;

    // per-lane K/V global bases (this wave's kv rows)
    const short* kp = Kh + ((size_t)(b * 4096 + wave * 16 + l15)) * 512
                      + h * 64 + quad * 8;
    const short* vbase = Vfrag + (size_t)(b * 8 + h) * 262144
                         + ((size_t)(wave * 4) * 64 + lane) * 8;

#define LDK(DST, I) { const short* _k = kp + (size_t)(I) * 65536;            \
    DST[0] = *(const f16x8*)(_k);                                            \
    DST[1] = *(const f16x8*)(_k + 32);                                       \
    DST[2] = *(const f16x8*)(_k + 32768);                                    \
    DST[3] = *(const f16x8*)(_k + 32800); }
#define LDV(DST, I) { const short* _v = vbase + (size_t)(I) * 8192;          \
    DST[0] = *(const f16x8*)(_v);                                            \
    DST[1] = *(const f16x8*)(_v + 512);                                      \
    DST[2] = *(const f16x8*)(_v + 1024);                                     \
    DST[3] = *(const f16x8*)(_v + 1536); }

#define QK(KC) {                                                             \
    __builtin_amdgcn_s_setprio(1);                                           \
    _Pragma("unroll")                                                        \
    for (int t = 0; t < 4; ++t) {                                            \
        s0[t] = MFMA16(KC[0], qf[t][0], zero4);                              \
        s0[t] = MFMA16(KC[1], qf[t][1], s0[t]);                              \
        s1[t] = MFMA16(KC[2], qf[t][0], zero4);                              \
        s1[t] = MFMA16(KC[3], qf[t][1], s1[t]);                              \
    }                                                                        \
    __builtin_amdgcn_s_setprio(0); }

#define FIN(VP) {                                                            \
    _Pragma("unroll")                                                        \
    for (int t = 0; t < 4; ++t) {                                            \
        float e0 = EXP2(s0[t][0]), e1 = EXP2(s0[t][1]);                      \
        float e2 = EXP2(s0[t][2]), e3 = EXP2(s0[t][3]);                      \
        float e4 = EXP2(s1[t][0]), e5 = EXP2(s1[t][1]);                      \
        float e6 = EXP2(s1[t][2]), e7 = EXP2(s1[t][3]);                      \
        i32x4 pw;                                                            \
        pw.x = __builtin_bit_cast(int, __builtin_amdgcn_cvt_pkrtz(e0, e1));  \
        pw.y = __builtin_bit_cast(int, __builtin_amdgcn_cvt_pkrtz(e2, e3));  \
        pw.z = __builtin_bit_cast(int, __builtin_amdgcn_cvt_pkrtz(e4, e5));  \
        pw.w = __builtin_bit_cast(int, __builtin_amdgcn_cvt_pkrtz(e6, e7));  \
        f16x8 p8 = __builtin_bit_cast(f16x8, pw);                            \
        __builtin_amdgcn_s_setprio(1);                                       \
        _Pragma("unroll")                                                    \
        for (int dt = 0; dt < 4; ++dt)                                       \
            o[t][dt] = MFMA16(p8, VP[dt], o[t][dt]);                         \
        l4[t] = MFMA16(p8, vones, l4[t]);                                    \
        __builtin_amdgcn_s_setprio(0);                                       \
    } }

    // BODY(I): K(I+1) loaded one body before use; V(I+1) two bodies before
    // use. I=31 prefetches tile 32 from adjacent allocated workspace.
#define BODY(I, KC, KN, VP) {                                                \
    LDK(KN, (I) + 1);                                                        \
    FIN(VP);                                                                 \
    LDV(VP, (I) + 1);                                                        \
    QK(KC); }

    f16x8 kA[4], kB[4], vA[4], vB[4];
    f32x4 s0[4], s1[4];

    // prologue: K0,V0,K1,V1 in flight; QK(0)
    LDK(kA, 0); LDV(vA, 0); LDK(kB, 1); LDV(vB, 1);
    QK(kA);

    #pragma unroll 1
    for (int j = 1; j < 31; j += 2) {
        BODY(j,     kB, kA, vA);
        BODY(j + 1, kA, kB, vB);
    }
    BODY(31, kB, kA, vA);
    FIN(vB);          // iter 31: s = QK(31), V(31) in vB

#undef BODY
#undef FIN
#undef QK
#undef LDV
#undef LDK

    float* Opart = (float*)smem;               // [4][64*33]
    float* Lpart = (float*)(smem + 33792);     // [4][64]

    // ---- two-pass cross-wave O reduction (pass 0: d 0..31, 1: 32..63) ----
    float inv_save[8];
    #pragma unroll
    for (int pass = 0; pass < 2; ++pass) {
        if (pass) __syncthreads();
        #pragma unroll
        for (int tq = 0; tq < 4; ++tq)
            #pragma unroll
            for (int dh = 0; dh < 2; ++dh) {
                int dt = pass * 2 + dh;
                #pragma unroll
                for (int r = 0; r < 4; ++r)
                    Opart[wave * (64 * 33) + (tq * 16 + quad * 4 + r) * 33 + dh * 16 + l15] = o[tq][dt][r];
            }
        if (pass == 0 && l15 == 0) {
            #pragma unroll
            for (int tq = 0; tq < 4; ++tq)
                #pragma unroll
                for (int r = 0; r < 4; ++r)
                    Lpart[wave * 64 + tq * 16 + quad * 4 + r] = l4[tq][r];
        }
        __syncthreads();
        #pragma unroll
        for (int r = 0; r < 8; ++r) {
            int qq = wave * 16 + r * 2 + (lane >> 5);
            int d  = lane & 31;
            float v = Opart[0 * (64 * 33) + qq * 33 + d] + Opart[1 * (64 * 33) + qq * 33 + d]
                    + Opart[2 * (64 * 33) + qq * 33 + d] + Opart[3 * (64 * 33) + qq * 33 + d];
            float inv;
            if (pass == 0) {
                float l = Lpart[qq] + Lpart[64 + qq] + Lpart[128 + qq] + Lpart[192 + qq];
                inv = 1.0f / l;
                inv_save[r] = inv;
            } else {
                inv = inv_save[r];
            }
            float val = v * inv;
            size_t oo = ((size_t)(b * 2048 + qb + qq)) * 512 + h * 64 + pass * 32 + d;
            AO[oo] = f2h(val);
        }
    }
}

// ---------------------------------------------------------------------------
extern "C" void kernel_launch(void* const* d_in, const int* in_sizes, int n_in,
                              void* d_out, int out_size, void* d_ws, size_t ws_size,
                              hipStream_t stream) {
    const float* q  = (const float*)d_in[0];
    const float* kv = (const float*)d_in[1];
    const float* Wq = (const float*)d_in[2];
    const float* bq = (const float*)d_in[3];
    const float* Wk = (const float*)d_in[4];
    const float* bk = (const float*)d_in[5];
    const float* Wv = (const float*)d_in[6];
    const float* bv = (const float*)d_in[7];
    const float* Wo = (const float*)d_in[8];
    const float* bo = (const float*)d_in[9];
    float* out = (float*)d_out;

    char* ws = (char*)d_ws;
    const size_t MB = 1024 * 1024;
    short* cq  = (short*)(ws + 0 * MB);    // 4 MB
    short* ckv = (short*)(ws + 4 * MB);    // 8 MB
    short* wq  = (short*)(ws + 12 * MB);   // 512 KB each
    short* wk  = wq + 262144;
    short* wv  = wk + 262144;
    short* wo  = wv + 262144;
    short* Qh  = (short*)(ws + 14 * MB);   // 4 MB
    short* Kh  = (short*)(ws + 18 * MB);   // 8 MB (tail K prefetch spills into Vf: allocated)
    short* Vf  = (short*)(ws + 26 * MB);   // 8 MB (tail V prefetch spills into AO: allocated)
    short* AO  = (short*)(ws + 34 * MB);   // 4 MB

    // 0.125 (1/sqrt(Dh)) * log2(e), so attention exp is a bare exp2.
    const float qscale = 0.18033688011112043f;

    dim3 blk(256);
    convert_kernel<<<7168, blk, 0, stream>>>(
        q, kv, Wq, Wk, Wv, Wo, cq, ckv, wq, wk, wv, wo);

    fused_qkv_gemm_kernel<<<1280, blk, 0, stream>>>(
        cq, ckv, wq, wk, wv, bq, bk, bv, qscale, Qh, Kh, Vf);

    rope_kernel<<<2048, blk, 0, stream>>>(Kh);

    attn_mfma_kernel<<<512, blk, 0, stream>>>(Qh, Kh, Vf, AO);

    gemm_o_kernel<<<256, blk, 0, stream>>>(AO, wo, bo, out);
}